// Round 16
// baseline (585.272 us; speedup 1.0000x reference)
//
#include <hip/hip_runtime.h>
#include <hip/hip_bf16.h>
#include <math.h>

// Sizes (fixed by the problem)
#define T_STEPS 1024
#define B_SZ 32
#define F_SZ 2048
#define H_SZ 64
#define G4 256      // 4*H
#define C_SZ 101

#define LOG2E 1.4426950408889634f

typedef __bf16 bf16x8 __attribute__((ext_vector_type(8)));
typedef unsigned short u16x8 __attribute__((ext_vector_type(8)));
typedef unsigned short u16x4 __attribute__((ext_vector_type(4)));
typedef float f32x4 __attribute__((ext_vector_type(4)));
typedef _Float16 f16x4 __attribute__((ext_vector_type(4)));
typedef _Float16 f16x8 __attribute__((ext_vector_type(8)));

// Round-to-nearest-even fp32 -> bf16 split: f ~= hi + lo (each bf16).
__device__ __forceinline__ void split_bf16(float f, unsigned short& h,
                                           unsigned short& l) {
  unsigned u = __builtin_bit_cast(unsigned, f);
  unsigned rh = (u + 0x7FFFu + ((u >> 16) & 1u)) >> 16;
  h = (unsigned short)rh;
  float d = f - __builtin_bit_cast(float, rh << 16);
  unsigned ud = __builtin_bit_cast(unsigned, d);
  l = (unsigned short)((ud + 0x7FFFu + ((ud >> 16) & 1u)) >> 16);
}

// 2^(-x) with the negate folded as a source modifier (zero extra VALU).
__device__ __forceinline__ float exp2_neg(float x) {
  float r;
  asm("v_exp_f32 %0, -%1" : "=v"(r) : "v"(x));
  return r;
}
// sigmoid of pre-scaled arg p' = p*log2e:  rcp(1 + 2^-p')
__device__ __forceinline__ float sig2(float pp) {
  return __builtin_amdgcn_rcpf(1.f + exp2_neg(pp));
}

// static 4-way select on precomputed lane bits (no runtime indexing)
__device__ __forceinline__ float sel4(float a0, float a1, float a2, float a3,
                                      bool k1, bool k2) {
  const float t0 = k1 ? a1 : a0;
  const float t1 = k1 ? a3 : a2;
  return k2 ? t1 : t0;
}

#define REP8(M) M(0) M(1) M(2) M(3) M(4) M(5) M(6) M(7)
#define REP16(M) M(0) M(1) M(2) M(3) M(4) M(5) M(6) M(7) \
                 M(8) M(9) M(10) M(11) M(12) M(13) M(14) M(15)

// ---------------------------------------------------------------------------
// Phase 0a: pre-split W_ih into bf16 hi/lo ONCE.
// ---------------------------------------------------------------------------
__global__ __launch_bounds__(256) void presplit_w(
    const float* __restrict__ W, unsigned short* __restrict__ hi,
    unsigned short* __restrict__ lo) {
  const int idx = (blockIdx.x * 256 + threadIdx.x) * 4;
  float4 v = *(const float4*)(W + idx);
  unsigned short h0, l0, h1, l1, h2, l2, h3, l3;
  split_bf16(v.x, h0, l0);
  split_bf16(v.y, h1, l1);
  split_bf16(v.z, h2, l2);
  split_bf16(v.w, h3, l3);
  *(u16x4*)(hi + idx) = u16x4{h0, h1, h2, h3};
  *(u16x4*)(lo + idx) = u16x4{l0, l1, l2, l3};
}

// ---------------------------------------------------------------------------
// Phase 0b: W_hh fp32 -> f16, PRE-SCALED into log2 domain:
// rows of gates i,f,o x log2e; rows of gate g x 2*log2e.
// ---------------------------------------------------------------------------
__global__ __launch_bounds__(256) void whh_to_f16(
    const float* __restrict__ W, _Float16* __restrict__ o) {
  const int idx = (blockIdx.x * 256 + threadIdx.x) * 4;
  const int row = idx >> 6;        // W_hh row (gate-col j)
  const int gate = row >> 6;       // 0..3
  const float s = (gate == 2) ? 2.f * LOG2E : LOG2E;
  float4 v = *(const float4*)(W + idx);
  f16x4 r = {(_Float16)(v.x * s), (_Float16)(v.y * s), (_Float16)(v.z * s),
             (_Float16)(v.w * s)};
  *(f16x4*)(o + idx) = r;
}

// ---------------------------------------------------------------------------
// Phase 1 (MFMA): xproj[t,b,j] = (sum_f x*W + b_ih + b_hh) * s_g  (log2 dom.)
// 128x256 tile, 8 waves, bf16-split 3-MFMA, BK=32; W pre-split from ws.
// ---------------------------------------------------------------------------
#define BM 128
#define BK 32
#define LDSP 40  // padded row stride in ushorts

__global__ __launch_bounds__(512) void xproj_mfma(
    const float* __restrict__ x, const unsigned short* __restrict__ Whi_g,
    const unsigned short* __restrict__ Wlo_g, const float* __restrict__ b_ih,
    const float* __restrict__ b_hh, float* __restrict__ xproj) {
  __shared__ alignas(16) unsigned short Xhi[BM][LDSP];
  __shared__ alignas(16) unsigned short Xlo[BM][LDSP];
  __shared__ alignas(16) unsigned short Whi[G4][LDSP];
  __shared__ alignas(16) unsigned short Wlo[G4][LDSP];

  const int tid = threadIdx.x;
  const int lane = tid & 63;
  const int wave = tid >> 6;  // 0..7
  const int wm = wave >> 2;   // 0..1 (M)
  const int wn = wave & 3;    // 0..3 (N)
  const size_t R0 = (size_t)blockIdx.x * BM;

  const int xr = tid >> 2;
  const int xs = (tid & 3) * 8;
  const int wr = tid >> 1;
  const int wsg = (tid & 1) * 16;

  const float* xbase = x + (R0 + xr) * (size_t)F_SZ + xs;
  const unsigned short* whb = Whi_g + (size_t)wr * F_SZ + wsg;
  const unsigned short* wlb = Wlo_g + (size_t)wr * F_SZ + wsg;

  float4 xa = *(const float4*)(xbase + 0);
  float4 xb = *(const float4*)(xbase + 4);
  u16x8 wh0 = *(const u16x8*)(whb + 0);
  u16x8 wh1 = *(const u16x8*)(whb + 8);
  u16x8 wl0 = *(const u16x8*)(wlb + 0);
  u16x8 wl1 = *(const u16x8*)(wlb + 8);

  f32x4 acc[4][4] = {};

  const int ar = lane & 15;
  const int ak = (lane >> 4) * 8;

  for (int kt = 0; kt < F_SZ; kt += BK) {
    {
      float xf[8] = {xa.x, xa.y, xa.z, xa.w, xb.x, xb.y, xb.z, xb.w};
      u16x8 xh, xl;
#pragma unroll
      for (int i = 0; i < 8; ++i) {
        unsigned short h, l;
        split_bf16(xf[i], h, l);
        xh[i] = h;
        xl[i] = l;
      }
      *(u16x8*)&Xhi[xr][xs] = xh;
      *(u16x8*)&Xlo[xr][xs] = xl;
      *(u16x8*)&Whi[wr][wsg] = wh0;
      *(u16x8*)&Whi[wr][wsg + 8] = wh1;
      *(u16x8*)&Wlo[wr][wsg] = wl0;
      *(u16x8*)&Wlo[wr][wsg + 8] = wl1;
    }
    __syncthreads();

    const int ktn = (kt + BK < F_SZ) ? kt + BK : kt;
    xa = *(const float4*)(xbase + ktn + 0);
    xb = *(const float4*)(xbase + ktn + 4);
    wh0 = *(const u16x8*)(whb + ktn + 0);
    wh1 = *(const u16x8*)(whb + ktn + 8);
    wl0 = *(const u16x8*)(wlb + ktn + 0);
    wl1 = *(const u16x8*)(wlb + ktn + 8);

    bf16x8 Ah[4], Al[4], Bh[4], Bl[4];
#pragma unroll
    for (int fm = 0; fm < 4; ++fm) {
      const int row = wm * 64 + fm * 16 + ar;
      Ah[fm] = __builtin_bit_cast(bf16x8, *(const u16x8*)&Xhi[row][ak]);
      Al[fm] = __builtin_bit_cast(bf16x8, *(const u16x8*)&Xlo[row][ak]);
    }
#pragma unroll
    for (int fn = 0; fn < 4; ++fn) {
      const int col = wn * 64 + fn * 16 + ar;
      Bh[fn] = __builtin_bit_cast(bf16x8, *(const u16x8*)&Whi[col][ak]);
      Bl[fn] = __builtin_bit_cast(bf16x8, *(const u16x8*)&Wlo[col][ak]);
    }
#pragma unroll
    for (int fm = 0; fm < 4; ++fm) {
#pragma unroll
      for (int fn = 0; fn < 4; ++fn) {
        acc[fm][fn] = __builtin_amdgcn_mfma_f32_16x16x32_bf16(
            Ah[fm], Bh[fn], acc[fm][fn], 0, 0, 0);
        acc[fm][fn] = __builtin_amdgcn_mfma_f32_16x16x32_bf16(
            Ah[fm], Bl[fn], acc[fm][fn], 0, 0, 0);
        acc[fm][fn] = __builtin_amdgcn_mfma_f32_16x16x32_bf16(
            Al[fm], Bh[fn], acc[fm][fn], 0, 0, 0);
      }
    }
    __syncthreads();
  }

  const int cr = (lane >> 4) * 4;
  const int cc = lane & 15;
#pragma unroll
  for (int fn = 0; fn < 4; ++fn) {
    const int gj = wn * 64 + fn * 16 + cc;
    const float bias = b_ih[gj] + b_hh[gj];
    // log2-domain pre-scale: gate g (cols 128..191) x 2log2e, others x log2e
    const float scale = (gj >= 128 && gj < 192) ? 2.f * LOG2E : LOG2E;
#pragma unroll
    for (int fm = 0; fm < 4; ++fm) {
      const size_t gr = R0 + wm * 64 + fm * 16 + cr;
#pragma unroll
      for (int r = 0; r < 4; ++r) {
        xproj[(gr + r) * G4 + gj] = (acc[fm][fn][r] + bias) * scale;
      }
    }
  }
}

// ---------------------------------------------------------------------------
// Phase 2: LSTM scan via MFMA broadcast trick, LOG2-DOMAIN activations and
// UN-CHAINED per-tile MFMAs.
//  - All inputs pre-scaled (xproj epilogue, whh_to_f16): every activation is
//    rcp(1+exp2(-p')) with the neg as a free src modifier — removes the
//    hidden x1.4427 muls of __expf from the critical path.
//  - c kept in scaled domain c' = 2log2e*c: c' = sf*c' + si*g', with
//    g' = 4log2e*r_g - 2log2e (one fma); tanh(c) = 2*rcp(1+exp2(-c'))-1.
//  - Per tile: accA = mfma(hA0,B0,zq), accB = mfma(hA1,B1,zq) INDEPENDENT
//    (R15 chained them: 2x MFMA dep latency on the path); summed post-select.
//  - Everything else R15-identical: counted-vmcnt x-pipeline, f16 parity
//    h-buffer, zero barriers, asm-volatile W pinning + waves_per_eu(1,1).
// ---------------------------------------------------------------------------
__global__ __attribute__((amdgpu_flat_work_group_size(64, 64)))
__attribute__((amdgpu_waves_per_eu(1, 1))) void lstm_scan_mfma(
    const float* __restrict__ xproj, const _Float16* __restrict__ Whh16,
    float* __restrict__ hT) {
  const int b = blockIdx.x;   // 0..31
  const int l = threadIdx.x;  // lane = unit u
  const int kg8 = (l >> 4) * 8;
  const bool k1 = ((l >> 4) & 1) != 0;
  const bool k2 = ((l >> 4) & 2) != 0;

  __shared__ alignas(16) _Float16 hbuf[2][H_SZ];

  // --- pin B-fragments: 16 tiles x 2 kslices = 32 quads = 128 VGPRs ---
  const _Float16* wb = Whh16 + (size_t)(l & 15) * H_SZ + kg8;
#define PINB(n)                                                               \
  f32x4 wB0_##n, wB1_##n;                                                     \
  {                                                                           \
    const _Float16* a0_##n = wb + (n) * (16 * H_SZ);                          \
    const _Float16* a1_##n = wb + (n) * (16 * H_SZ) + 32;                     \
    asm volatile("global_load_dwordx4 %0, %1, off" : "=v"(wB0_##n) : "v"(a0_##n)); \
    asm volatile("global_load_dwordx4 %0, %1, off" : "=v"(wB1_##n) : "v"(a1_##n)); \
  }
  REP16(PINB)
#undef PINB
  asm volatile("s_waitcnt vmcnt(0)" ::: "memory");

  // persistent zero quad (opaque; stays in registers)
  f32x4 zq = {0.f, 0.f, 0.f, 0.f};
  asm volatile("" : "+v"(zq));

  hbuf[0][l] = (_Float16)0.f;
  float cq = 0.f, hval = 0.f;  // cq = c' = 2log2e * c
  int p = 0;

  const float* a_next = xproj + (size_t)b * G4 + l;
  const size_t step_off = (size_t)B_SZ * G4;  // floats per t

  float xi0, xf0, xg0, xo0, xi1, xf1, xg1, xo1;
  float xi2, xf2, xg2, xo2, xi3, xf3, xg3, xo3;

#define XLOAD(S, a)                                                     \
  asm volatile("global_load_dword %0, %4, off\n\t"                      \
               "global_load_dword %1, %4, off offset:256\n\t"           \
               "global_load_dword %2, %4, off offset:512\n\t"           \
               "global_load_dword %3, %4, off offset:768"               \
               : "=&v"(xi##S), "=&v"(xf##S), "=&v"(xg##S), "=&v"(xo##S) \
               : "v"(a));

  // prologue: t = 0..3 in flight (16 outstanding)
  XLOAD(0, a_next) a_next += step_off;
  XLOAD(1, a_next) a_next += step_off;
  XLOAD(2, a_next) a_next += step_off;
  XLOAD(3, a_next) a_next += step_off;  // points at t=4

  for (int it = 0; it < T_STEPS / 4; ++it) {
    const int tb = it * 4;

#define TILE(n)                                                               \
    f32x4 accA_##n, accB_##n;                                                 \
    accA_##n = __builtin_amdgcn_mfma_f32_16x16x32_f16(                        \
        hA0, __builtin_bit_cast(f16x8, wB0_##n), zq, 0, 0, 0);                \
    accB_##n = __builtin_amdgcn_mfma_f32_16x16x32_f16(                        \
        hA1, __builtin_bit_cast(f16x8, wB1_##n), zq, 0, 0, 0);

#define SLOT(S)                                                               \
    {                                                                         \
      /* h broadcast first: start the LDS latency ASAP */                     \
      const f16x8 hA0 = *(const f16x8*)&hbuf[p][kg8];                         \
      const f16x8 hA1 = *(const f16x8*)&hbuf[p][32 + kg8];                    \
      REP16(TILE)                                                             \
      /* oldest 4 x-loads retire; 12 stay in flight (needed only now) */      \
      asm volatile("s_waitcnt vmcnt(12)"                                      \
                   : "+v"(xi##S), "+v"(xf##S), "+v"(xg##S), "+v"(xo##S));     \
      const float di = sel4(accA_0[0], accA_1[0], accA_2[0], accA_3[0], k1, k2)   \
                     + sel4(accB_0[0], accB_1[0], accB_2[0], accB_3[0], k1, k2);  \
      const float df = sel4(accA_4[0], accA_5[0], accA_6[0], accA_7[0], k1, k2)   \
                     + sel4(accB_4[0], accB_5[0], accB_6[0], accB_7[0], k1, k2);  \
      const float dg = sel4(accA_8[0], accA_9[0], accA_10[0], accA_11[0], k1, k2) \
                     + sel4(accB_8[0], accB_9[0], accB_10[0], accB_11[0], k1, k2);\
      const float dq = sel4(accA_12[0], accA_13[0], accA_14[0], accA_15[0], k1, k2)   \
                     + sel4(accB_12[0], accB_13[0], accB_14[0], accB_15[0], k1, k2);  \
      const float pi = xi##S + di;                                            \
      const float pf = xf##S + df;                                            \
      const float pg = xg##S + dg;                                            \
      const float po = xo##S + dq;                                            \
      const float si = sig2(pi);                                              \
      const float sf = sig2(pf);                                              \
      const float so = sig2(po);                                              \
      const float rg = sig2(pg);                                              \
      const float gt = __builtin_fmaf(rg, 4.f * LOG2E, -2.f * LOG2E);         \
      cq = __builtin_fmaf(sf, cq, si * gt);                                   \
      const float tc = __builtin_fmaf(sig2(cq), 2.f, -1.f);                   \
      hval = so * tc;                                                         \
      hbuf[p ^ 1][l] = (_Float16)hval;                                        \
      p ^= 1;                                                                 \
      /* re-issue set S for t+4 (clamped addr near tail; never consumed) */   \
      XLOAD(S, a_next)                                                        \
      if (tb + (S) + 4 < T_STEPS - 1) a_next += step_off;                     \
    }

    SLOT(0)
    SLOT(1)
    SLOT(2)
    SLOT(3)

#undef SLOT
#undef TILE
  }
#undef XLOAD

  hT[b * H_SZ + l] = hval;
}

// ---------------------------------------------------------------------------
// Phase 3: out[b][c] = sum_k hT[b][k] * W_lin[c][k] + b_lin[c]
// ---------------------------------------------------------------------------
__global__ __launch_bounds__(128) void final_linear_kernel(
    const float* __restrict__ hT, const float* __restrict__ W_lin,
    const float* __restrict__ b_lin, float* __restrict__ out) {
  const int b = blockIdx.x;
  const int cc = threadIdx.x;

  __shared__ float h_l[H_SZ];
  if (threadIdx.x < H_SZ) h_l[threadIdx.x] = hT[b * H_SZ + threadIdx.x];
  __syncthreads();

  if (cc < C_SZ) {
    float acc = b_lin[cc];
    const float* wr = W_lin + (size_t)cc * H_SZ;
#pragma unroll
    for (int k = 0; k < H_SZ; ++k) acc += h_l[k] * wr[k];
    out[b * C_SZ + cc] = acc;
  }
}

// ---------------------------------------------------------------------------
extern "C" void kernel_launch(void* const* d_in, const int* in_sizes, int n_in,
                              void* d_out, int out_size, void* d_ws,
                              size_t ws_size, hipStream_t stream) {
  const float* x = (const float*)d_in[0];      // [T,B,F]
  const float* W_ih = (const float*)d_in[1];   // [4H,F]
  const float* W_hh = (const float*)d_in[2];   // [4H,H]
  const float* b_ih = (const float*)d_in[3];   // [4H]
  const float* b_hh = (const float*)d_in[4];   // [4H]
  const float* W_lin = (const float*)d_in[5];  // [C,H]
  const float* b_lin = (const float*)d_in[6];  // [C]
  float* out = (float*)d_out;                  // [B,C]

  // ws layout: xproj 32MB | hT 8KB | Whi 1MB | Wlo 1MB | Whh_f16 32KB
  const size_t XP_BYTES = (size_t)T_STEPS * B_SZ * G4 * sizeof(float);
  float* xproj = (float*)d_ws;
  float* hT = (float*)((char*)d_ws + XP_BYTES);
  unsigned short* Whi_g = (unsigned short*)((char*)d_ws + XP_BYTES + 8192);
  unsigned short* Wlo_g = Whi_g + (size_t)G4 * F_SZ;
  _Float16* Whh16 = (_Float16*)(Wlo_g + (size_t)G4 * F_SZ);

  presplit_w<<<512, 256, 0, stream>>>(W_ih, Whi_g, Wlo_g);
  whh_to_f16<<<16, 256, 0, stream>>>(W_hh, Whh16);
  xproj_mfma<<<(T_STEPS * B_SZ) / BM, 512, 0, stream>>>(x, Whi_g, Wlo_g, b_ih,
                                                        b_hh, xproj);
  lstm_scan_mfma<<<B_SZ, 64, 0, stream>>>(xproj, Whh16, hT);
  final_linear_kernel<<<B_SZ, 128, 0, stream>>>(hT, W_lin, b_lin, out);
}

// Round 17
// 484.154 us; speedup vs baseline: 1.2089x; 1.2089x over previous
//
#include <hip/hip_runtime.h>
#include <hip/hip_bf16.h>
#include <math.h>

// Sizes (fixed by the problem)
#define T_STEPS 1024
#define B_SZ 32
#define F_SZ 2048
#define H_SZ 64
#define G4 256      // 4*H
#define C_SZ 101

typedef unsigned short u16x8 __attribute__((ext_vector_type(8)));
typedef unsigned short u16x4 __attribute__((ext_vector_type(4)));
typedef float f32x4 __attribute__((ext_vector_type(4)));
typedef _Float16 f16x4 __attribute__((ext_vector_type(4)));
typedef _Float16 f16x8 __attribute__((ext_vector_type(8)));

__device__ __forceinline__ unsigned short f2h(float f) {
  _Float16 h = (_Float16)f;
  return __builtin_bit_cast(unsigned short, h);
}

__device__ __forceinline__ float sigm_f(float x) {
  return __builtin_amdgcn_rcpf(1.f + __expf(-x));
}
__device__ __forceinline__ float tanh_f(float x) {
  return 2.f * __builtin_amdgcn_rcpf(1.f + __expf(-2.f * x)) - 1.f;
}

// static 4-way select on precomputed lane bits (no runtime indexing)
__device__ __forceinline__ float sel4(float a0, float a1, float a2, float a3,
                                      bool k1, bool k2) {
  const float t0 = k1 ? a1 : a0;
  const float t1 = k1 ? a3 : a2;
  return k2 ? t1 : t0;
}

#define REP16(M) M(0) M(1) M(2) M(3) M(4) M(5) M(6) M(7) \
                 M(8) M(9) M(10) M(11) M(12) M(13) M(14) M(15)

// ---------------------------------------------------------------------------
// Phase 0: convert W_ih AND W_hh to f16 in ONE kernel.
// blocks 0..511: W_ih (256x2048); blocks 512..527: W_hh (256x64).
// ---------------------------------------------------------------------------
__global__ __launch_bounds__(256) void conv_w(
    const float* __restrict__ Wih, const float* __restrict__ Whh,
    _Float16* __restrict__ o_ih, _Float16* __restrict__ o_hh) {
  const int bid = blockIdx.x;
  if (bid < 512) {
    const int idx = (bid * 256 + threadIdx.x) * 4;
    float4 v = *(const float4*)(Wih + idx);
    f16x4 r = {(_Float16)v.x, (_Float16)v.y, (_Float16)v.z, (_Float16)v.w};
    *(f16x4*)(o_ih + idx) = r;
  } else {
    const int idx = ((bid - 512) * 256 + threadIdx.x) * 4;
    float4 v = *(const float4*)(Whh + idx);
    f16x4 r = {(_Float16)v.x, (_Float16)v.y, (_Float16)v.z, (_Float16)v.w};
    *(f16x4*)(o_hh + idx) = r;
  }
}

// ---------------------------------------------------------------------------
// Phase 1: xproj[t,b,j] = sum_f x[t,b,f]*W_ih[j,f] + b_ih[j] + b_hh[j]
// SINGLE f16 MFMA (was 3x bf16-split): f16 rel err 2^-11 -> xproj abs err
// ~6e-4 << 2.2e-3 threshold. 3x fewer MFMAs, 2x less LDS (30KB), no split
// VALU in staging. 128x256 tile, 8 waves, BK=32, W pre-converted in ws.
// ---------------------------------------------------------------------------
#define BM 128
#define BK 32
#define LDSP 40  // padded row stride in ushorts

__global__ __launch_bounds__(512) void xproj_f16(
    const float* __restrict__ x, const _Float16* __restrict__ Wih16,
    const float* __restrict__ b_ih, const float* __restrict__ b_hh,
    float* __restrict__ xproj) {
  __shared__ alignas(16) unsigned short Xf[BM][LDSP];
  __shared__ alignas(16) unsigned short Wf[G4][LDSP];

  const int tid = threadIdx.x;
  const int lane = tid & 63;
  const int wave = tid >> 6;  // 0..7
  const int wm = wave >> 2;   // 0..1 (M)
  const int wn = wave & 3;    // 0..3 (N)
  const size_t R0 = (size_t)blockIdx.x * BM;

  const int xr = tid >> 2;          // 0..127
  const int xs = (tid & 3) * 8;     // 0,8,16,24
  const int wr = tid >> 1;          // 0..255
  const int wsg = (tid & 1) * 16;   // 0,16

  const float* xbase = x + (R0 + xr) * (size_t)F_SZ + xs;
  const unsigned short* wbase =
      (const unsigned short*)Wih16 + (size_t)wr * F_SZ + wsg;

  // prologue prefetch (tile kt=0)
  float4 xa = *(const float4*)(xbase + 0);
  float4 xb = *(const float4*)(xbase + 4);
  u16x8 wh0 = *(const u16x8*)(wbase + 0);
  u16x8 wh1 = *(const u16x8*)(wbase + 8);

  f32x4 acc[4][4] = {};

  const int ar = lane & 15;
  const int ak = (lane >> 4) * 8;

  for (int kt = 0; kt < F_SZ; kt += BK) {
    // ---- stage: convert x fp32 -> f16, store W f16 raw ----
    {
      u16x8 xh;
      xh[0] = f2h(xa.x);
      xh[1] = f2h(xa.y);
      xh[2] = f2h(xa.z);
      xh[3] = f2h(xa.w);
      xh[4] = f2h(xb.x);
      xh[5] = f2h(xb.y);
      xh[6] = f2h(xb.z);
      xh[7] = f2h(xb.w);
      *(u16x8*)&Xf[xr][xs] = xh;
      *(u16x8*)&Wf[wr][wsg] = wh0;
      *(u16x8*)&Wf[wr][wsg + 8] = wh1;
    }
    __syncthreads();

    // ---- prefetch next K-tile ----
    const int ktn = (kt + BK < F_SZ) ? kt + BK : kt;
    xa = *(const float4*)(xbase + ktn + 0);
    xb = *(const float4*)(xbase + ktn + 4);
    wh0 = *(const u16x8*)(wbase + ktn + 0);
    wh1 = *(const u16x8*)(wbase + ktn + 8);

    // ---- fragments + MFMA (1 per fm,fn) ----
    f16x8 A[4], Bv[4];
#pragma unroll
    for (int fm = 0; fm < 4; ++fm) {
      const int row = wm * 64 + fm * 16 + ar;
      A[fm] = __builtin_bit_cast(f16x8, *(const u16x8*)&Xf[row][ak]);
    }
#pragma unroll
    for (int fn = 0; fn < 4; ++fn) {
      const int col = wn * 64 + fn * 16 + ar;
      Bv[fn] = __builtin_bit_cast(f16x8, *(const u16x8*)&Wf[col][ak]);
    }
#pragma unroll
    for (int fm = 0; fm < 4; ++fm) {
#pragma unroll
      for (int fn = 0; fn < 4; ++fn) {
        acc[fm][fn] = __builtin_amdgcn_mfma_f32_16x16x32_f16(
            A[fm], Bv[fn], acc[fm][fn], 0, 0, 0);
      }
    }
    __syncthreads();
  }

  const int cr = (lane >> 4) * 4;
  const int cc = lane & 15;
#pragma unroll
  for (int fn = 0; fn < 4; ++fn) {
    const int gj = wn * 64 + fn * 16 + cc;
    const float bias = b_ih[gj] + b_hh[gj];
#pragma unroll
    for (int fm = 0; fm < 4; ++fm) {
      const size_t gr = R0 + wm * 64 + fm * 16 + cr;
#pragma unroll
      for (int r = 0; r < 4; ++r) {
        xproj[(gr + r) * G4 + gj] = acc[fm][fn][r] + bias;
      }
    }
  }
}

// ---------------------------------------------------------------------------
// Phase 2: LSTM scan via MFMA broadcast trick (R15 form — best measured:
// 385us) + FUSED final linear (saves a launch; h is lane/LDS-resident).
//  - One wave per batch, zero barriers, f16 weights pinned in 128 VGPRs
//    (asm volatile + waves_per_eu(1,1)); counted-vmcnt x-pipeline with 4
//    named register sets; chained 2-MFMA per tile; persistent zero quad.
//  - After the t-loop: hval (fp32, exact) -> LDS; each lane computes
//    out[b][l] and out[b][64+l] (if <101) with fp32 dots.
// ---------------------------------------------------------------------------
__global__ __attribute__((amdgpu_flat_work_group_size(64, 64)))
__attribute__((amdgpu_waves_per_eu(1, 1))) void lstm_scan_mfma(
    const float* __restrict__ xproj, const _Float16* __restrict__ Whh16,
    const float* __restrict__ W_lin, const float* __restrict__ b_lin,
    float* __restrict__ out) {
  const int b = blockIdx.x;   // 0..31
  const int l = threadIdx.x;  // lane = unit u
  const int kg8 = (l >> 4) * 8;
  const bool k1 = ((l >> 4) & 1) != 0;
  const bool k2 = ((l >> 4) & 2) != 0;

  __shared__ alignas(16) _Float16 hbuf[2][H_SZ];
  __shared__ alignas(16) float hfin[H_SZ];

  // --- pin B-fragments: 16 tiles x 2 kslices = 32 quads = 128 VGPRs ---
  const _Float16* wb = Whh16 + (size_t)(l & 15) * H_SZ + kg8;
#define PINB(n)                                                               \
  f32x4 wB0_##n, wB1_##n;                                                     \
  {                                                                           \
    const _Float16* a0_##n = wb + (n) * (16 * H_SZ);                          \
    const _Float16* a1_##n = wb + (n) * (16 * H_SZ) + 32;                     \
    asm volatile("global_load_dwordx4 %0, %1, off" : "=v"(wB0_##n) : "v"(a0_##n)); \
    asm volatile("global_load_dwordx4 %0, %1, off" : "=v"(wB1_##n) : "v"(a1_##n)); \
  }
  REP16(PINB)
#undef PINB
  asm volatile("s_waitcnt vmcnt(0)" ::: "memory");

  // persistent zero quad (opaque; stays in registers)
  f32x4 zq = {0.f, 0.f, 0.f, 0.f};
  asm volatile("" : "+v"(zq));

  hbuf[0][l] = (_Float16)0.f;
  float c = 0.f, hval = 0.f;
  int p = 0;

  const float* a_next = xproj + (size_t)b * G4 + l;
  const size_t step_off = (size_t)B_SZ * G4;  // floats per t

  float xi0, xf0, xg0, xo0, xi1, xf1, xg1, xo1;
  float xi2, xf2, xg2, xo2, xi3, xf3, xg3, xo3;

#define XLOAD(S, a)                                                     \
  asm volatile("global_load_dword %0, %4, off\n\t"                      \
               "global_load_dword %1, %4, off offset:256\n\t"           \
               "global_load_dword %2, %4, off offset:512\n\t"           \
               "global_load_dword %3, %4, off offset:768"               \
               : "=&v"(xi##S), "=&v"(xf##S), "=&v"(xg##S), "=&v"(xo##S) \
               : "v"(a));

  // prologue: t = 0..3 in flight (16 outstanding)
  XLOAD(0, a_next) a_next += step_off;
  XLOAD(1, a_next) a_next += step_off;
  XLOAD(2, a_next) a_next += step_off;
  XLOAD(3, a_next) a_next += step_off;  // points at t=4

  for (int it = 0; it < T_STEPS / 4; ++it) {
    const int tb = it * 4;

#define TILE(n)                                                               \
    f32x4 acc_##n;                                                            \
    acc_##n = __builtin_amdgcn_mfma_f32_16x16x32_f16(                         \
        hA0, __builtin_bit_cast(f16x8, wB0_##n), zq, 0, 0, 0);                \
    acc_##n = __builtin_amdgcn_mfma_f32_16x16x32_f16(                         \
        hA1, __builtin_bit_cast(f16x8, wB1_##n), acc_##n, 0, 0, 0);

#define SLOT(S)                                                               \
    {                                                                         \
      /* oldest 4 x-loads retire; 12 stay in flight */                        \
      asm volatile("s_waitcnt vmcnt(12)"                                      \
                   : "+v"(xi##S), "+v"(xf##S), "+v"(xg##S), "+v"(xo##S));     \
      /* A fragments: same h quad for every lane in a k-group (broadcast) */  \
      const f16x8 hA0 = *(const f16x8*)&hbuf[p][kg8];                         \
      const f16x8 hA1 = *(const f16x8*)&hbuf[p][32 + kg8];                    \
      REP16(TILE)                                                             \
      /* gate g of unit l: tile g*4+(l>>4), col l&15; rows identical */       \
      const float di = sel4(acc_0[0], acc_1[0], acc_2[0], acc_3[0], k1, k2);  \
      const float df = sel4(acc_4[0], acc_5[0], acc_6[0], acc_7[0], k1, k2);  \
      const float dg = sel4(acc_8[0], acc_9[0], acc_10[0], acc_11[0], k1, k2);\
      const float dq = sel4(acc_12[0], acc_13[0], acc_14[0], acc_15[0], k1, k2);\
      const float pi = xi##S + di;                                            \
      const float pf = xf##S + df;                                            \
      const float pg = xg##S + dg;                                            \
      const float po = xo##S + dq;                                            \
      c = sigm_f(pf) * c + sigm_f(pi) * tanh_f(pg);                           \
      hval = sigm_f(po) * tanh_f(c);                                          \
      hbuf[p ^ 1][l] = (_Float16)hval;                                        \
      p ^= 1;                                                                 \
      /* re-issue set S for t+4 (clamped addr near tail; never consumed) */   \
      XLOAD(S, a_next)                                                        \
      if (tb + (S) + 4 < T_STEPS - 1) a_next += step_off;                     \
    }

    SLOT(0)
    SLOT(1)
    SLOT(2)
    SLOT(3)

#undef SLOT
#undef TILE
  }
#undef XLOAD

  // ---- fused final linear: out[b][cc] = h . W_lin[cc] + b_lin[cc] ----
  hfin[l] = hval;  // fp32, exact; same-wave lgkmcnt ordering (no barrier)

  {
    float acc0 = b_lin[l];
    const float* wr0 = W_lin + (size_t)l * H_SZ;
#pragma unroll
    for (int k = 0; k < 16; ++k) {
      const float4 w = *(const float4*)(wr0 + 4 * k);
      const float4 h = *(const float4*)&hfin[4 * k];
      acc0 += w.x * h.x + w.y * h.y + w.z * h.z + w.w * h.w;
    }
    out[b * C_SZ + l] = acc0;

    const int c1 = l + 64;
    if (c1 < C_SZ) {
      float acc1 = b_lin[c1];
      const float* wr1 = W_lin + (size_t)c1 * H_SZ;
#pragma unroll
      for (int k = 0; k < 16; ++k) {
        const float4 w = *(const float4*)(wr1 + 4 * k);
        const float4 h = *(const float4*)&hfin[4 * k];
        acc1 += w.x * h.x + w.y * h.y + w.z * h.z + w.w * h.w;
      }
      out[b * C_SZ + c1] = acc1;
    }
  }
}

// ---------------------------------------------------------------------------
extern "C" void kernel_launch(void* const* d_in, const int* in_sizes, int n_in,
                              void* d_out, int out_size, void* d_ws,
                              size_t ws_size, hipStream_t stream) {
  const float* x = (const float*)d_in[0];      // [T,B,F]
  const float* W_ih = (const float*)d_in[1];   // [4H,F]
  const float* W_hh = (const float*)d_in[2];   // [4H,H]
  const float* b_ih = (const float*)d_in[3];   // [4H]
  const float* b_hh = (const float*)d_in[4];   // [4H]
  const float* W_lin = (const float*)d_in[5];  // [C,H]
  const float* b_lin = (const float*)d_in[6];  // [C]
  float* out = (float*)d_out;                  // [B,C]

  // ws layout: xproj 32MB | Wih_f16 1MB | Whh_f16 32KB
  const size_t XP_BYTES = (size_t)T_STEPS * B_SZ * G4 * sizeof(float);
  float* xproj = (float*)d_ws;
  _Float16* Wih16 = (_Float16*)((char*)d_ws + XP_BYTES);
  _Float16* Whh16 = Wih16 + (size_t)G4 * F_SZ;

  conv_w<<<528, 256, 0, stream>>>(W_ih, W_hh, Wih16, Whh16);
  xproj_f16<<<(T_STEPS * B_SZ) / BM, 512, 0, stream>>>(x, Wih16, b_ih, b_hh,
                                                       xproj);
  lstm_scan_mfma<<<B_SZ, 64, 0, stream>>>(xproj, Whh16, W_lin, b_lin, out);
}